// Round 9
// baseline (369.252 us; speedup 1.0000x reference)
//
#include <hip/hip_runtime.h>
#include <hip/hip_bf16.h>
#include <math.h>

#define NN 1329
#define FF 130
#define BB 16
#define TT 24
#define HH 15
#define KK 5
#define BT (BB*TT)      // 384
#define G4 (4*HH)       // 60

// ---- MFMA geometry ----
#define KPAD 1344
#define NKC 42          // k-chunks of 32
#define MFRAG 88        // row-frags of 16
#define NMT 11          // m-tiles of 128 rows
#define NCF 9           // col-frags of 16 (F=130 padded to 144)
#define NBTF 24         // bt-frags of 16 (384/16)
#define NKCO 44         // kcg slots for Y2A (11 mt * 4; slots 42,43 zero rows)
#define NBTP 192        // bt pairs: block covers bt and bt+192

typedef __attribute__((ext_vector_type(8))) short short8v;   // 8 bf16
typedef __attribute__((ext_vector_type(4))) float f32x4;

// ---- workspace layout (float offsets) ----
#define OFS_ROWSUM 0
#define OFS_SPAD   1408
#define OFS_Y1     (OFS_SPAD + BT*KPAD)
#define OFS_END_F  (OFS_Y1 + BT*NN)
#define ABF_ELEMS  (NKC*MFRAG*64*8)     // 1,892,352 ushorts
#define WBF_ELEMS  (NKC*NCF*64*8)       //   193,536 ushorts
#define WTB_ELEMS  (NKC*4*64*8)         //    86,016 ushorts
#define Y2A_ELEMS  (NKCO*NBTF*64*8)     //   540,672 ushorts

__device__ __forceinline__ float sigmoidf(float x) { return 1.f / (1.f + expf(-x)); }

__device__ __forceinline__ unsigned short bf16rne(float x) {
    unsigned u = __float_as_uint(x);
    return (unsigned short)((u + 0x7fffu + ((u >> 16) & 1u)) >> 16);
}
__device__ __forceinline__ float bf16lo(unsigned a) { return __uint_as_float(a << 16); }
__device__ __forceinline__ float bf16hi(unsigned a) { return __uint_as_float(a & 0xffff0000u); }
// hardware packed f32->bf16 (RNE), 1 instr per pair
__device__ __forceinline__ unsigned cvtpk2(float lo, float hi) {
    unsigned r;
    asm volatile("v_cvt_pk_bf16_f32 %0, %1, %2" : "=v"(r) : "v"(lo), "v"(hi));
    return r;
}

__device__ __forceinline__ void gll16(const void* g, void* l) {
    __builtin_amdgcn_global_load_lds((const __attribute__((address_space(1))) unsigned*)g,
                                     (__attribute__((address_space(3))) unsigned*)l, 16, 0, 0);
}

// ================= fused prep (aprep | wprep | sprep | wihTbf | rowsum) =================
#define NB_APREP 924
#define NB_WPREP 95
#define NB_SPREP 2016
#define NB_WTB   42
#define NB_ROWS  NN
#define NB_PREP  (NB_APREP+NB_WPREP+NB_SPREP+NB_WTB+NB_ROWS)

__global__ __launch_bounds__(256) void k_prep(
    const float* __restrict__ A, const float* __restrict__ W,
    const float* __restrict__ seq, const float* __restrict__ Wih,
    unsigned short* __restrict__ Abf, unsigned short* __restrict__ Wbf,
    float* __restrict__ spad, unsigned short* __restrict__ WihTbf, float* __restrict__ rowsum)
{
    __shared__ float r4[4];
    const int bid = blockIdx.x;
    const int tid = threadIdx.x;
    if (bid < NB_APREP) {
        int s = bid*256 + tid;
        int l = s & 63;
        int t = s >> 6;
        int mf = t % MFRAG;
        int kcg = t / MFRAG;
        int m = mf*16 + (l & 15);
        int kb = kcg*32 + (l >> 4)*8;
        union { uint4 u4; unsigned short us[8]; } ow;
#pragma unroll
        for (int j = 0; j < 8; j++) {
            int k = kb + j;
            float x = (m < NN && k < NN) ? A[(size_t)m*NN + k] : 0.f;
            ow.us[j] = bf16rne(x);
        }
        *(uint4*)(Abf + (size_t)s*8) = ow.u4;
    } else if (bid < NB_APREP+NB_WPREP) {
        int s = (bid-NB_APREP)*256 + tid;
        if (s < NKC*NCF*64) {
            int l = s & 63;
            int t = s >> 6;
            int cf = t % NCF;
            int kcg = t / NCF;
            int f = cf*16 + (l & 15);
            int kb = kcg*32 + (l >> 4)*8;
            union { uint4 u4; unsigned short us[8]; } ow;
#pragma unroll
            for (int j = 0; j < 8; j++) {
                int k = kb + j;
                float x = (k < NN && f < FF) ? W[(size_t)k*FF + f] : 0.f;
                ow.us[j] = bf16rne(x);
            }
            *(uint4*)(Wbf + (size_t)s*8) = ow.u4;
        }
    } else if (bid < NB_APREP+NB_WPREP+NB_SPREP) {
        int idx = (bid-NB_APREP-NB_WPREP)*256 + tid;   // < BT*KPAD exactly
        int bt = idx / KPAD;
        int k  = idx - bt*KPAD;
        spad[idx] = (k < NN) ? seq[(size_t)bt*NN + k] : 0.f;
    } else if (bid < NB_APREP+NB_WPREP+NB_SPREP+NB_WTB) {
        int s = (bid-NB_APREP-NB_WPREP-NB_SPREP)*256 + tid;   // < NKC*4*64 exactly
        int l = s & 63;
        int t = s >> 6;
        int gf = t & 3;
        int kcg = t >> 2;
        int g = gf*16 + (l & 15);
        int nb = kcg*32 + (l >> 4)*8;
        union { uint4 u4; unsigned short us[8]; } ow;
#pragma unroll
        for (int j = 0; j < 8; j++) {
            int n = nb + j;
            float x = (g < G4 && n < NN) ? Wih[(size_t)g*NN + n] : 0.f;
            ow.us[j] = bf16rne(x);
        }
        *(uint4*)(WihTbf + (size_t)s*8) = ow.u4;
    } else {
        int m = bid - (NB_APREP+NB_WPREP+NB_SPREP+NB_WTB);
        float a = 0.f;
        for (int n = tid; n < NN; n += 256) a += A[(size_t)m*NN + n];
#pragma unroll
        for (int off = 32; off; off >>= 1) a += __shfl_down(a, off, 64);
        if ((tid & 63) == 0) r4[tid >> 6] = a;
        __syncthreads();
        if (tid == 0) rowsum[m] = r4[0]+r4[1]+r4[2]+r4[3];
    }
}

// ============ GCN layer 1: bf16 MFMA, 2 bt per block (A-frags shared), B dbuf in LDS ============
__global__ __launch_bounds__(256,2) void k_gcn1(
    const unsigned short* __restrict__ Abf, const unsigned short* __restrict__ Wbf,
    const float* __restrict__ spad,
    const float* __restrict__ bias, const float* __restrict__ w2, const float* __restrict__ bias2,
    const float* __restrict__ rowsum, float* __restrict__ Y1)
{
    __shared__ __align__(16) short Blds[2][NCF*64*8];   // 2 x 9 KB

    const int id = blockIdx.x;
    const int mt = id / NBTP;
    const int btp = id - mt*NBTP;
    const int bt0 = btp, bt1 = btp + NBTP;
    const int m0 = mt*128;
    const int tid = threadIdx.x;
    const int lane = tid & 63;
    const int wv = tid >> 6;
    const float* sba = spad + (size_t)bt0*KPAD;
    const float* sbb = spad + (size_t)bt1*KPAD;
    const int klane = (lane >> 4)*8;

    f32x4 accA[2][NCF], accB[2][NCF];
#pragma unroll
    for (int rf = 0; rf < 2; rf++)
#pragma unroll
        for (int cf = 0; cf < NCF; cf++) {
            accA[rf][cf] = (f32x4){0.f, 0.f, 0.f, 0.f};
            accB[rf][cf] = (f32x4){0.f, 0.f, 0.f, 0.f};
        }

    auto stageB = [&](int kcg, int nb) {
        const unsigned short* wsrc = Wbf + (size_t)kcg*(NCF*64*8);
#pragma unroll
        for (int it = 0; it < 2; ++it) {
            int slot = it*256 + tid;
            gll16(wsrc + (size_t)slot*8, &Blds[nb][slot*8]);
        }
        if (tid < 64) {
            int slot = 512 + tid;
            gll16(wsrc + (size_t)slot*8, &Blds[nb][slot*8]);
        }
    };
    uint4 r0, r1;
    float4 s0a, s1a, s0b, s1b;
    auto loadA = [&](int kcg) {
        const unsigned short* p = Abf + ((size_t)(kcg*MFRAG + mt*8 + 2*wv)*64 + lane)*8;
        r0 = *(const uint4*)p;
        r1 = *(const uint4*)(p + 64*8);
        const float* spa = sba + kcg*32 + klane;
        s0a = *(const float4*)spa;
        s1a = *(const float4*)(spa + 4);
        const float* spb = sbb + kcg*32 + klane;
        s0b = *(const float4*)spb;
        s1b = *(const float4*)(spb + 4);
    };
    auto scaleA = [&](uint4 r, float4 s0, float4 s1) -> short8v {
        union { uint4 u4; short8v s8; } o;
        o.u4.x = cvtpk2(bf16lo(r.x)*s0.x, bf16hi(r.x)*s0.y);
        o.u4.y = cvtpk2(bf16lo(r.y)*s0.z, bf16hi(r.y)*s0.w);
        o.u4.z = cvtpk2(bf16lo(r.z)*s1.x, bf16hi(r.z)*s1.y);
        o.u4.w = cvtpk2(bf16lo(r.w)*s1.z, bf16hi(r.w)*s1.w);
        return o.s8;
    };

    stageB(0, 0);
    loadA(0);
    __syncthreads();
    short8v a0a = scaleA(r0, s0a, s1a), a1a = scaleA(r1, s0a, s1a);
    short8v a0b = scaleA(r0, s0b, s1b), a1b = scaleA(r1, s0b, s1b);

    for (int t = 0; t < NKC; ++t) {
        const int cur = t & 1;
        if (t + 1 < NKC) { stageB(t+1, cur^1); loadA(t+1); }
#pragma unroll
        for (int cf = 0; cf < NCF; cf++) {
            short8v bfr = *(const short8v*)&Blds[cur][(cf*64 + lane)*8];
            accA[0][cf] = __builtin_amdgcn_mfma_f32_16x16x32_bf16(a0a, bfr, accA[0][cf], 0, 0, 0);
            accA[1][cf] = __builtin_amdgcn_mfma_f32_16x16x32_bf16(a1a, bfr, accA[1][cf], 0, 0, 0);
            accB[0][cf] = __builtin_amdgcn_mfma_f32_16x16x32_bf16(a0b, bfr, accB[0][cf], 0, 0, 0);
            accB[1][cf] = __builtin_amdgcn_mfma_f32_16x16x32_bf16(a1b, bfr, accB[1][cf], 0, 0, 0);
        }
        if (t + 1 < NKC) {
            a0a = scaleA(r0, s0a, s1a); a1a = scaleA(r1, s0a, s1a);
            a0b = scaleA(r0, s0b, s1b); a1b = scaleA(r1, s0b, s1b);
        }
        __syncthreads();
    }

    // ---- epilogue x2: relu(X + bias*rowsum) dot w2, butterfly over 16 f-lanes ----
    const int fcol = lane & 15;
    const int rgrp = lane >> 4;
    float bv[NCF], wv2[NCF];
#pragma unroll
    for (int cf = 0; cf < NCF; cf++) {
        int f = cf*16 + fcol;
        bv[cf]  = (f < FF) ? bias[f] : 0.f;
        wv2[cf] = (f < FF) ? w2[f]   : 0.f;
    }
    float b2 = bias2[0];
#pragma unroll
    for (int half = 0; half < 2; half++) {
        int btv = half ? bt1 : bt0;
#pragma unroll
        for (int rf = 0; rf < 2; rf++) {
#pragma unroll
            for (int r = 0; r < 4; r++) {
                int m = m0 + (2*wv + rf)*16 + rgrp*4 + r;
                float rs = (m < NN) ? rowsum[m] : 0.f;
                float p = 0.f;
#pragma unroll
                for (int cf = 0; cf < NCF; cf++) {
                    float x = (half ? accB[rf][cf][r] : accA[rf][cf][r]) + bv[cf]*rs;
                    p += fmaxf(x, 0.f) * wv2[cf];
                }
                p += __shfl_xor(p, 1, 64);
                p += __shfl_xor(p, 2, 64);
                p += __shfl_xor(p, 4, 64);
                p += __shfl_xor(p, 8, 64);
                if (fcol == 0 && m < NN) Y1[(size_t)btv*NN + m] = p + b2;
            }
        }
    }
}

// ======= GCN layer 2: full-K bf16 MFMA, B from fp32 Y1 inline; epilogue relu -> Y2A (A-frag bf16) =======
__global__ __launch_bounds__(256) void k_gcn2(
    const unsigned short* __restrict__ Abf, const float* __restrict__ Y1,
    unsigned short* __restrict__ Y2A)
{
    const int mt  = blockIdx.x;     // 11
    const int btg = blockIdx.y;     // 12 (32 bt each)
    const int tid = threadIdx.x;
    const int lane = tid & 63;
    const int wv = tid >> 6;
    const int q = lane >> 4;

    f32x4 acc[2][2];
#pragma unroll
    for (int rf = 0; rf < 2; rf++)
#pragma unroll
        for (int cf = 0; cf < 2; cf++) acc[rf][cf] = (f32x4){0.f, 0.f, 0.f, 0.f};

    const float* y1r0 = Y1 + (size_t)((btg*2 + 0)*16 + (lane & 15))*NN;
    const float* y1r1 = Y1 + (size_t)((btg*2 + 1)*16 + (lane & 15))*NN;
    const int nq = q*8;

    for (int kcg = 0; kcg < NKC; ++kcg) {
        const unsigned short* ap = Abf + ((size_t)(kcg*MFRAG + mt*8 + 2*wv)*64 + lane)*8;
        short8v a0 = *(const short8v*)ap;
        short8v a1 = *(const short8v*)(ap + 64*8);
        int n0 = kcg*32 + nq;
        union { uint4 u4; short8v s8; } b0, b1;
        if (kcg < NKC-1) {
            float4 x0 = *(const float4*)(y1r0 + n0);
            float4 x1 = *(const float4*)(y1r0 + n0 + 4);
            b0.u4.x = cvtpk2(x0.x, x0.y); b0.u4.y = cvtpk2(x0.z, x0.w);
            b0.u4.z = cvtpk2(x1.x, x1.y); b0.u4.w = cvtpk2(x1.z, x1.w);
            float4 y0 = *(const float4*)(y1r1 + n0);
            float4 y1v = *(const float4*)(y1r1 + n0 + 4);
            b1.u4.x = cvtpk2(y0.x, y0.y); b1.u4.y = cvtpk2(y0.z, y0.w);
            b1.u4.z = cvtpk2(y1v.x, y1v.y); b1.u4.w = cvtpk2(y1v.z, y1v.w);
        } else {
            float xa[8], xb[8];
#pragma unroll
            for (int j = 0; j < 8; j++) {
                int n = n0 + j;
                xa[j] = (n < NN) ? y1r0[n] : 0.f;
                xb[j] = (n < NN) ? y1r1[n] : 0.f;
            }
            b0.u4.x = cvtpk2(xa[0], xa[1]); b0.u4.y = cvtpk2(xa[2], xa[3]);
            b0.u4.z = cvtpk2(xa[4], xa[5]); b0.u4.w = cvtpk2(xa[6], xa[7]);
            b1.u4.x = cvtpk2(xb[0], xb[1]); b1.u4.y = cvtpk2(xb[2], xb[3]);
            b1.u4.z = cvtpk2(xb[4], xb[5]); b1.u4.w = cvtpk2(xb[6], xb[7]);
        }
        acc[0][0] = __builtin_amdgcn_mfma_f32_16x16x32_bf16(a0, b0.s8, acc[0][0], 0, 0, 0);
        acc[1][0] = __builtin_amdgcn_mfma_f32_16x16x32_bf16(a1, b0.s8, acc[1][0], 0, 0, 0);
        acc[0][1] = __builtin_amdgcn_mfma_f32_16x16x32_bf16(a0, b1.s8, acc[0][1], 0, 0, 0);
        acc[1][1] = __builtin_amdgcn_mfma_f32_16x16x32_bf16(a1, b1.s8, acc[1][1], 0, 0, 0);
    }

    const int kcgo = mt*4 + wv;
    const int jofs = (q & 1)*4;
#pragma unroll
    for (int rf = 0; rf < 2; rf++) {
        int lp = (rf*2 + (q >> 1))*16 + (lane & 15);
#pragma unroll
        for (int cf = 0; cf < 2; cf++) {
            int btf = btg*2 + cf;
            uint2 w2v;
            w2v.x = cvtpk2(fmaxf(acc[rf][cf][0], 0.f), fmaxf(acc[rf][cf][1], 0.f));
            w2v.y = cvtpk2(fmaxf(acc[rf][cf][2], 0.f), fmaxf(acc[rf][cf][3], 0.f));
            *(uint2*)(Y2A + ((size_t)(kcgo*NBTF + btf)*64 + lp)*8 + jofs) = w2v;
        }
    }
}

// ======= fused tail: xW (MFMA) -> LSTM (wave 0) -> heads (all threads); 1 block per batch b =======
__global__ __launch_bounds__(256) void k_tail(
    const unsigned short* __restrict__ Y2A, const unsigned short* __restrict__ WihTbf,
    const float* __restrict__ Whh, const float* __restrict__ bih, const float* __restrict__ bhh,
    const float* __restrict__ h0, const float* __restrict__ c0,
    const float* __restrict__ fc_w, const float* __restrict__ fc_b, float* __restrict__ out)
{
    __shared__ float xw_lds[2][16][64];
    __shared__ float h_s[16];
    __shared__ float s_sh[16];

    const int b = blockIdx.x;
    const int tid = threadIdx.x;
    const int lane = tid & 63;
    const int wv = tid >> 6;
    const int f0 = (24*b) >> 4;    // first bt-frag needed by this block

    // ---- phase 1: xW fragments f0, f0+1 via MFMA (waves 0,1) ----
    if (wv < 2) {
        const int fw = f0 + wv;
        f32x4 a4[4];
#pragma unroll
        for (int gf = 0; gf < 4; gf++) a4[gf] = (f32x4){0.f, 0.f, 0.f, 0.f};
        for (int kcg = 0; kcg < NKC; ++kcg) {
            short8v a = *(const short8v*)(Y2A + ((size_t)(kcg*NBTF + fw)*64 + lane)*8);
#pragma unroll
            for (int gf = 0; gf < 4; gf++) {
                short8v bm = *(const short8v*)(WihTbf + ((size_t)(kcg*4 + gf)*64 + lane)*8);
                a4[gf] = __builtin_amdgcn_mfma_f32_16x16x32_bf16(a, bm, a4[gf], 0, 0, 0);
            }
        }
#pragma unroll
        for (int gf = 0; gf < 4; gf++)
#pragma unroll
            for (int r = 0; r < 4; r++)
                xw_lds[wv][(lane >> 4)*4 + r][gf*16 + (lane & 15)] = a4[gf][r];
    }
    __syncthreads();

    // ---- phase 2: LSTM recurrence, wave 0 only (same-wave LDS, no barriers) ----
    if (wv == 0) {
        float whh_r[HH];
        float bs = 0.f;
        if (lane < G4) {
            bs = bih[lane] + bhh[lane];
#pragma unroll
            for (int k = 0; k < HH; k++) whh_r[k] = Whh[lane*HH + k];
        }
        float c_r = 0.f, h_last = 0.f;
        if (lane < HH) { h_s[lane] = h0[b*HH + lane]; c_r = c0[b*HH + lane]; }
        for (int t = 0; t < TT; ++t) {
            int fidx = 24*b + t - f0*16;
            float v = 0.f;
            if (lane < G4) {
                v = xw_lds[fidx >> 4][fidx & 15][lane] + bs;
#pragma unroll
                for (int k = 0; k < HH; k++) v = fmaf(whh_r[k], h_s[k], v);
            }
            float vi = __shfl(v, lane, 64);
            float vf = __shfl(v, HH   + lane, 64);
            float vg = __shfl(v, 2*HH + lane, 64);
            float vo = __shfl(v, 3*HH + lane, 64);
            if (lane < HH) {
                float c = sigmoidf(vf)*c_r + sigmoidf(vi)*tanhf(vg);
                c_r = c;
                float h = sigmoidf(vo)*tanhf(c);
                h_s[lane] = h;
                h_last = h;
            }
        }
        if (lane < HH) s_sh[lane] = sigmoidf(h_last);
    }
    __syncthreads();

    // ---- phase 3: 5 FC heads for this batch element (all 256 threads) ----
    for (int idx = tid; idx < KK*NN; idx += 256) {
        int k = idx / NN;
        int n = idx - k*NN;
        const float* wp = fc_w + (size_t)idx*HH;
        float v = fc_b[idx];
#pragma unroll
        for (int h = 0; h < HH; h++) v = fmaf(wp[h], s_sh[h], v);
        out[((size_t)k*BB + b)*NN + n] = tanhf(v);
    }
}

extern "C" void kernel_launch(void* const* d_in, const int* in_sizes, int n_in,
                              void* d_out, int out_size, void* d_ws, size_t ws_size,
                              hipStream_t stream) {
    const float* seq   = (const float*)d_in[0];
    const float* A     = (const float*)d_in[1];
    const float* W     = (const float*)d_in[2];
    const float* bias  = (const float*)d_in[3];
    const float* w2    = (const float*)d_in[4];
    const float* bias2 = (const float*)d_in[5];
    const float* Wih   = (const float*)d_in[6];
    const float* Whh   = (const float*)d_in[7];
    const float* bih   = (const float*)d_in[8];
    const float* bhh   = (const float*)d_in[9];
    const float* h0    = (const float*)d_in[10];
    const float* c0    = (const float*)d_in[11];
    const float* fcw   = (const float*)d_in[12];
    const float* fcb   = (const float*)d_in[13];
    float* ws = (float*)d_ws;
    float* rowsum = ws + OFS_ROWSUM;
    float* spad   = ws + OFS_SPAD;
    float* Y1     = ws + OFS_Y1;
    unsigned short* Abf    = (unsigned short*)(ws + OFS_END_F);
    unsigned short* Wbf    = Abf + ABF_ELEMS;
    unsigned short* WihTbf = Wbf + WBF_ELEMS;
    unsigned short* Y2A    = WihTbf + WTB_ELEMS;
    float* out = (float*)d_out;

    hipLaunchKernelGGL(k_prep, dim3(NB_PREP), dim3(256), 0, stream,
                       A, W, seq, Wih, Abf, Wbf, spad, WihTbf, rowsum);
    hipLaunchKernelGGL(k_gcn1, dim3(NMT*NBTP), dim3(256), 0, stream,
                       Abf, Wbf, spad, bias, w2, bias2, rowsum, Y1);
    hipLaunchKernelGGL(k_gcn2, dim3(NMT, 12), dim3(256), 0, stream, Abf, Y1, Y2A);
    hipLaunchKernelGGL(k_tail, dim3(BB), dim3(256), 0, stream,
                       Y2A, WihTbf, Whh, bih, bhh, h0, c0, fcw, fcb, out);
}